// Round 4
// baseline (264.333 us; speedup 1.0000x reference)
//
#include <hip/hip_runtime.h>
#include <stdint.h>

typedef unsigned int u32;
typedef unsigned short u16;
typedef float f32x4 __attribute__((ext_vector_type(4)));
typedef __fp16 h16x2 __attribute__((ext_vector_type(2)));   // cvt_pkrtz native type
typedef _Float16 f16x8 __attribute__((ext_vector_type(8)));
typedef float f4u __attribute__((ext_vector_type(4), aligned(4)));  // 4B-aligned vec load

#define NB   8
#define CIN  256
#define HH   64
#define WW   64
#define HW   4096
#define COUT 256
#define NPX  128   // pixels per block (2 output rows)
#define BSTR 264   // u16 per Bs row (256 + 8 pad; 528B = 33*16B)

__device__ __forceinline__ u32 pkh(float lo, float hi) {
  h16x2 h = __builtin_amdgcn_cvt_pkrtz(lo, hi);   // v_cvt_pkrtz_f16_f32, 1 instr
  return __builtin_bit_cast(u32, h);
}
union HU { u32 u; h16x2 h; };

// ---- prep_all: blocks 0..2047 transpose x -> xT (fp16 NHWC); rest weights ----
// W2f frag layout: frag = (kk*8+cc)*16 + tile; element: lane*8+j ;
// co = (tile>>2)*64 + (tile&3)*16 + (lane&15); c = cc*32 + (lane>>4)*8 + j.
__global__ __launch_bounds__(256) void prep_all(const float* __restrict__ x,
                                                const float* __restrict__ wgt,
                                                u32* __restrict__ xT,
                                                u32* __restrict__ W2f32) {
  int b = blockIdx.x;
  int t = threadIdx.x;
  if (b < 2048) {
    __shared__ __align__(16) u32 tile[16][132];
    int n = b >> 8, hw0 = (b & 255) << 4;
    int hwq = (t & 3) << 2;          // 0,4,8,12
    int cp0 = t >> 2;                // 0..63
    const float* xb = x + (size_t)n * CIN * HW + hw0 + hwq;
#pragma unroll
    for (int it = 0; it < 2; ++it) {
      int cp = (it << 6) + cp0;      // 0..127
      int c = cp << 1;
      f4u v0 = *(const f4u*)(xb + (size_t)c * HW);
      f4u v1 = *(const f4u*)(xb + (size_t)(c + 1) * HW);
      tile[hwq + 0][cp] = pkh(v0.x, v1.x);
      tile[hwq + 1][cp] = pkh(v0.y, v1.y);
      tile[hwq + 2][cp] = pkh(v0.z, v1.z);
      tile[hwq + 3][cp] = pkh(v0.w, v1.w);
    }
    __syncthreads();
    u32* outp = xT + ((size_t)(n * HW + hw0)) * 128;
    int cq = t & 31, hb = t >> 5;    // cq: uint4 col 0..31, hb: row 0..7
#pragma unroll
    for (int it = 0; it < 2; ++it) {
      int hwl = (it << 3) + hb;
      uint4 v = *(const uint4*)&tile[hwl][cq << 2];   // ds_read_b128, 16B-aligned
      *(uint4*)(outp + (size_t)hwl * 128 + (cq << 2)) = v;  // 512B/half-wave
    }
  } else {
    // weights: thread = (co, c-pair); reads 18 consecutive floats
    int tt = (b - 2048) * 256 + t;   // 32768 total
    int cp = tt & 127, co = tt >> 7;
    int c = cp << 1;
    const float* p = wgt + ((size_t)co * CIN + c) * 9;
    f4u q0 = *(const f4u*)(p + 0);
    f4u q1 = *(const f4u*)(p + 4);
    f4u q2 = *(const f4u*)(p + 8);
    f4u q3 = *(const f4u*)(p + 12);
    float e16 = p[16], e17 = p[17];
    float a0[9], a1[9];
    a0[0]=q0.x; a0[1]=q0.y; a0[2]=q0.z; a0[3]=q0.w;
    a0[4]=q1.x; a0[5]=q1.y; a0[6]=q1.z; a0[7]=q1.w; a0[8]=q2.x;
    a1[0]=q2.y; a1[1]=q2.z; a1[2]=q2.w;
    a1[3]=q3.x; a1[4]=q3.y; a1[5]=q3.z; a1[6]=q3.w; a1[7]=e16; a1[8]=e17;
    int cc = c >> 5;
    int j = (c >> 1) & 3;
    int lane = (co & 15) | (((c >> 3) & 3) << 4);
    int tile_ = ((co >> 6) << 2) | ((co >> 4) & 3);
#pragma unroll
    for (int kk = 0; kk < 9; ++kk) {
      int frag = (kk * 8 + cc) * 16 + tile_;
      W2f32[(size_t)frag * 256 + lane * 4 + j] = pkh(a0[kk], a1[kk]);
    }
  }
}

// ---- main: 256 blocks x 1024 threads; block = 256 Cout x 128 px (2 rows) ----
// 16 waves: strip = w&7 (32 Cout), parity = w>>3 (even/odd K-chunks).
// r4 change vs the 60.3us base: weight (af) fragments register-prefetched ONE
// TAP AHEAD (afr[8]). Old order gathers->af->MFMA made the MFMA's af wait
// drain the gather FIFO too (vmcnt(0)): a full L2 round-trip serialized before
// every g's MFMA cluster. Now MFMA reads regs (no VMEM wait) and combine
// waits vmcnt(2) (own gathers only; af-next stays in flight).
__global__ __launch_bounds__(1024, 4) void dcn_main(
    const float* __restrict__ offset, const float* __restrict__ mask,
    const float* __restrict__ bias, const u16* __restrict__ xT,
    const u16* __restrict__ W2f, float* __restrict__ out) {
  __shared__ __align__(16) u16 Bs[2][NPX * BSTR];  // 2 x 67.6 KB
  __shared__ __align__(8)  uint2 swl[1152];        // (kk,p): 4 corner wts, fp16 pairs
  __shared__ __align__(8)  ushort4 sol[1152];      // (kk,p): 4 corner position indices

  int bid = blockIdx.x;      // 256 blocks = 1/CU
  int n = bid & 7;           // XCD swizzle: XCD k serves n==k -> 2MB xT slice in L2
  int hp = bid >> 3;         // ho-pair 0..31
  int t = threadIdx.x;
  int lane = t & 63;
  int w = t >> 6;            // wave 0..15

  // 1) sample precompute: 9 taps x 128 px
  for (int i = t; i < 1152; i += 1024) {
    int kk = i >> 7, p = i & 127;
    int ky = kk / 3, kx = kk - ky * 3;
    int sp = (hp << 7) + p;             // = ho*64 + (p&63)
    int ho = (hp << 1) + (p >> 6);
    float dy = offset[(((size_t)n * 18 + kk * 2 + 0) << 12) + sp];
    float dx = offset[(((size_t)n * 18 + kk * 2 + 1) << 12) + sp];
    float m  = mask  [(((size_t)n * 9  + kk) << 12) + sp];
    float ys = (float)(ky + ho - 1) + dy;
    float xs = (float)(kx + (p & 63) - 1) + dx;
    float y0f = floorf(ys), x0f = floorf(xs);
    float fy = ys - y0f, fx = xs - x0f;
    int y0 = (int)y0f, x0 = (int)x0f;
    int y1 = y0 + 1, x1 = x0 + 1;
    float vy0 = (y0 >= 0 && y0 < HH) ? 1.f : 0.f;
    float vy1 = (y1 >= 0 && y1 < HH) ? 1.f : 0.f;
    float vx0 = (x0 >= 0 && x0 < WW) ? 1.f : 0.f;
    float vx1 = (x1 >= 0 && x1 < WW) ? 1.f : 0.f;
    float w0 = (1.f - fy) * (1.f - fx) * m * vy0 * vx0;
    float w1 = (1.f - fy) * fx * m * vy0 * vx1;
    float w2 = fy * (1.f - fx) * m * vy1 * vx0;
    float w3 = fy * fx * m * vy1 * vx1;
    int iy0 = min(max(y0, 0), HH - 1), iy1 = min(max(y1, 0), HH - 1);
    int ix0 = min(max(x0, 0), WW - 1), ix1 = min(max(x1, 0), WW - 1);
    ushort4 pv;
    pv.x = (u16)((iy0 << 6) + ix0);
    pv.y = (u16)((iy0 << 6) + ix1);
    pv.z = (u16)((iy1 << 6) + ix0);
    pv.w = (u16)((iy1 << 6) + ix1);
    swl[i] = make_uint2(pkh(w0, w1), pkh(w2, w3));
    sol[i] = pv;
  }
  __syncthreads();

  f32x4 acc[2][8];
#pragma unroll
  for (int a = 0; a < 2; ++a)
#pragma unroll
    for (int b2 = 0; b2 < 8; ++b2) acc[a][b2] = {0.f, 0.f, 0.f, 0.f};

  const char* xTn = (const char*)xT + ((size_t)n * HW << 9);
  int ml = lane & 15, q = lane >> 4;
  int hw32 = t >> 5;     // half-wave id 0..31: builds px = g*32 + hw32
  int l32 = t & 31;
  int strip = w & 7, pr = w >> 3;                     // Cout strip / cc parity
  int tile0 = ((strip >> 1) << 2) + ((strip & 1) << 1);
  const char* bch = xTn + (l32 << 4);

// accumulate one register-resident corner (8 v_fma_mix_f32)
#define CMB(G, WT) do {                                                \
    float wt = (WT);                                                   \
    HU h0, h1, h2, h3;                                                 \
    h0.u = (G).x; h1.u = (G).y; h2.u = (G).z; h3.u = (G).w;            \
    s0 = __builtin_fmaf((float)h0.h.x, wt, s0);                        \
    s1 = __builtin_fmaf((float)h0.h.y, wt, s1);                        \
    s2 = __builtin_fmaf((float)h1.h.x, wt, s2);                        \
    s3 = __builtin_fmaf((float)h1.h.y, wt, s3);                        \
    s4 = __builtin_fmaf((float)h2.h.x, wt, s4);                        \
    s5 = __builtin_fmaf((float)h2.h.y, wt, s5);                        \
    s6 = __builtin_fmaf((float)h3.h.x, wt, s6);                        \
    s7 = __builtin_fmaf((float)h3.h.y, wt, s7);                        \
  } while (0)

  // monolithic build for the prologue (tap 0 into buf 0)
  auto build0 = [&](int g) {
    int px = (g << 5) + hw32;
    uint2 wu = swl[px];
    ushort4 pv = sol[px];
    HU ha, hb; ha.u = wu.x; hb.u = wu.y;
    uint4 G0 = *(const uint4*)(bch + ((int)pv.x << 9));
    uint4 G1 = *(const uint4*)(bch + ((int)pv.y << 9));
    uint4 G2 = *(const uint4*)(bch + ((int)pv.z << 9));
    uint4 G3 = *(const uint4*)(bch + ((int)pv.w << 9));
    float s0=0.f,s1=0.f,s2=0.f,s3=0.f,s4=0.f,s5=0.f,s6=0.f,s7=0.f;
    CMB(G0, (float)ha.h.x);
    CMB(G1, (float)ha.h.y);
    CMB(G2, (float)hb.h.x);
    CMB(G3, (float)hb.h.y);
    uint4 pkd;
    pkd.x = pkh(s0, s1); pkd.y = pkh(s2, s3);
    pkd.z = pkh(s4, s5); pkd.w = pkh(s6, s7);
    *(uint4*)((char*)&Bs[0][0] + px * (BSTR * 2) + (l32 << 4)) = pkd;
  };

  auto af_load = [&](int fidx, int mt) {
    return *(const f16x8*)(W2f + (((size_t)((fidx << 4) + tile0 + mt)) << 9) +
                           (lane << 3));
  };

  // register-prefetched A fragments for the CURRENT tap: afr[g*2+mt]
  f16x8 afr[8];
#pragma unroll
  for (int g = 0; g < 4; ++g) {
    int cc = (g << 1) | pr;
    afr[(g << 1) + 0] = af_load(cc, 0);   // tap 0 frags
    afr[(g << 1) + 1] = af_load(cc, 1);
  }

#pragma unroll
  for (int g = 0; g < 4; ++g) build0(g);
  __syncthreads();

#pragma unroll 1
  for (int kk = 0; kk < 9; ++kk) {
    int cur = kk & 1;
    char* Bw = (char*)&Bs[cur ^ 1][0];
    const char* Br = (const char*)&Bs[cur][0];
#pragma unroll
    for (int g = 0; g < 4; ++g) {
      int px = (g << 5) + hw32;
      int cc = (g << 1) | pr;
      uint4 G0, G1, G2, G3;
      if (kk < 8) {        // EARLY: issue next-tap gathers for this px-group
        ushort4 pv = sol[((kk + 1) << 7) + px];
        G0 = *(const uint4*)(bch + ((int)pv.x << 9));
        G1 = *(const uint4*)(bch + ((int)pv.y << 9));
        G2 = *(const uint4*)(bch + ((int)pv.z << 9));
        G3 = *(const uint4*)(bch + ((int)pv.w << 9));
      }
      f16x8 afn0, afn1;
      if (kk < 8) {        // prefetch NEXT tap's weights (consumed next kk)
        afn0 = af_load(((kk + 1) << 3) + cc, 0);
        afn1 = af_load(((kk + 1) << 3) + cc, 1);
      }
      // this wave's K-chunk for this g: af from registers, zero VMEM wait
      {
        f16x8 af0 = afr[(g << 1) + 0];
        f16x8 af1 = afr[(g << 1) + 1];
        f16x8 bf[4];
#pragma unroll
        for (int half = 0; half < 2; ++half) {
#pragma unroll
          for (int j = 0; j < 4; ++j)
            bf[j] = *(const f16x8*)(Br +
                    ((((half << 2) + j) << 4) + ml) * (BSTR * 2) +
                    (cc << 6) + (q << 4));
#pragma unroll
          for (int j = 0; j < 4; ++j)
            acc[0][(half << 2) + j] = __builtin_amdgcn_mfma_f32_16x16x32_f16(
                af0, bf[j], acc[0][(half << 2) + j], 0, 0, 0);
#pragma unroll
          for (int j = 0; j < 4; ++j)
            acc[1][(half << 2) + j] = __builtin_amdgcn_mfma_f32_16x16x32_f16(
                af1, bf[j], acc[1][(half << 2) + j], 0, 0, 0);
        }
      }
      if (kk < 8) {        // LATE: combine (waits own gathers, vmcnt(2)) + write
        uint2 wu = swl[((kk + 1) << 7) + px];
        HU ha, hb; ha.u = wu.x; hb.u = wu.y;
        float s0=0.f,s1=0.f,s2=0.f,s3=0.f,s4=0.f,s5=0.f,s6=0.f,s7=0.f;
        CMB(G0, (float)ha.h.x);
        CMB(G1, (float)ha.h.y);
        CMB(G2, (float)hb.h.x);
        CMB(G3, (float)hb.h.y);
        uint4 pkd;
        pkd.x = pkh(s0, s1); pkd.y = pkh(s2, s3);
        pkd.z = pkh(s4, s5); pkd.w = pkh(s6, s7);
        *(uint4*)(Bw + px * (BSTR * 2) + (l32 << 4)) = pkd;
      }
      if (kk < 8) {        // rotate prefetched A frags into place
        afr[(g << 1) + 0] = afn0;
        afr[(g << 1) + 1] = afn1;
      }
    }
    __syncthreads();   // all waves done reading Bs[cur] / writing Bs[cur^1]
  }

  // epilogue: pair-reduce parity partials through LDS (reuse Bs: 33792 floats)
  float* PS = (float*)&Bs[0][0];
  float* P = PS + strip * 4224 + lane * 66;   // 66-stride: 2-way banks (free)
  if (pr) {
#pragma unroll
    for (int mt = 0; mt < 2; ++mt)
#pragma unroll
      for (int nt = 0; nt < 8; ++nt)
#pragma unroll
        for (int r = 0; r < 4; ++r)
          P[((mt << 3) + nt) * 4 + r] = acc[mt][nt][r];
  }
  __syncthreads();
  if (!pr) {
    // D layout: row = q*4+r, col = ml (m91-verified); px = nt*16+ml
    size_t ob = (size_t)n * COUT * HW + ((size_t)hp << 7);
#pragma unroll
    for (int mt = 0; mt < 2; ++mt) {
#pragma unroll
      for (int r = 0; r < 4; ++r) {
        int co = (strip << 5) + (mt << 4) + (q << 2) + r;
        float bv = bias[co];
#pragma unroll
        for (int nt = 0; nt < 8; ++nt) {
          int px = (nt << 4) + ml;
          out[ob + (size_t)co * HW + px] =
              acc[mt][nt][r] + P[((mt << 3) + nt) * 4 + r] + bv;
        }
      }
    }
  }
}

extern "C" void kernel_launch(void* const* d_in, const int* in_sizes, int n_in,
                              void* d_out, int out_size, void* d_ws, size_t ws_size,
                              hipStream_t stream) {
  const float* x      = (const float*)d_in[0];
  const float* offset = (const float*)d_in[1];
  const float* mask   = (const float*)d_in[2];
  const float* weight = (const float*)d_in[3];
  const float* bias   = (const float*)d_in[4];
  float* out = (float*)d_out;

  u16* xT  = (u16*)d_ws;                                      // 16 MB fp16
  u16* W2f = (u16*)((char*)d_ws + (size_t)NB * HW * CIN * 2); // +1.18 MB fp16

  prep_all<<<2176, 256, 0, stream>>>(x, weight, (u32*)xT, (u32*)W2f);
  dcn_main<<<256, 1024, 0, stream>>>(offset, mask, bias, xT, W2f, out);
}

// Round 5
// 150.645 us; speedup vs baseline: 1.7547x; 1.7547x over previous
//
#include <hip/hip_runtime.h>
#include <stdint.h>

typedef unsigned int u32;
typedef unsigned short u16;
typedef float f32x4 __attribute__((ext_vector_type(4)));
typedef __fp16 h16x2 __attribute__((ext_vector_type(2)));   // cvt_pkrtz native type
typedef _Float16 f16x8 __attribute__((ext_vector_type(8)));
typedef float f4u __attribute__((ext_vector_type(4), aligned(4)));  // 4B-aligned vec load

#define NB   8
#define CIN  256
#define HH   64
#define WW   64
#define HW   4096
#define COUT 256
#define NPX  128   // pixels per block (2 output rows)
#define BSTR 264   // u16 per Bs row (256 + 8 pad; 528B = 33*16B)

__device__ __forceinline__ u32 pkh(float lo, float hi) {
  h16x2 h = __builtin_amdgcn_cvt_pkrtz(lo, hi);   // v_cvt_pkrtz_f16_f32, 1 instr
  return __builtin_bit_cast(u32, h);
}
union HU { u32 u; h16x2 h; };

// ---- prep_all: blocks 0..2047 transpose x -> xT (fp16 NHWC); rest weights ----
// W2f frag layout: frag = (kk*8+cc)*16 + tile; element: lane*8+j ;
// co = (tile>>2)*64 + (tile&3)*16 + (lane&15); c = cc*32 + (lane>>4)*8 + j.
__global__ __launch_bounds__(256) void prep_all(const float* __restrict__ x,
                                                const float* __restrict__ wgt,
                                                u32* __restrict__ xT,
                                                u32* __restrict__ W2f32) {
  int b = blockIdx.x;
  int t = threadIdx.x;
  if (b < 2048) {
    __shared__ __align__(16) u32 tile[16][132];
    int n = b >> 8, hw0 = (b & 255) << 4;
    int hwq = (t & 3) << 2;          // 0,4,8,12
    int cp0 = t >> 2;                // 0..63
    const float* xb = x + (size_t)n * CIN * HW + hw0 + hwq;
#pragma unroll
    for (int it = 0; it < 2; ++it) {
      int cp = (it << 6) + cp0;      // 0..127
      int c = cp << 1;
      f4u v0 = *(const f4u*)(xb + (size_t)c * HW);
      f4u v1 = *(const f4u*)(xb + (size_t)(c + 1) * HW);
      tile[hwq + 0][cp] = pkh(v0.x, v1.x);
      tile[hwq + 1][cp] = pkh(v0.y, v1.y);
      tile[hwq + 2][cp] = pkh(v0.z, v1.z);
      tile[hwq + 3][cp] = pkh(v0.w, v1.w);
    }
    __syncthreads();
    u32* outp = xT + ((size_t)(n * HW + hw0)) * 128;
    int cq = t & 31, hb = t >> 5;    // cq: uint4 col 0..31, hb: row 0..7
#pragma unroll
    for (int it = 0; it < 2; ++it) {
      int hwl = (it << 3) + hb;
      uint4 v = *(const uint4*)&tile[hwl][cq << 2];   // ds_read_b128, 16B-aligned
      *(uint4*)(outp + (size_t)hwl * 128 + (cq << 2)) = v;  // 512B/half-wave
    }
  } else {
    // weights: thread = (co, c-pair); reads 18 consecutive floats
    int tt = (b - 2048) * 256 + t;   // 32768 total
    int cp = tt & 127, co = tt >> 7;
    int c = cp << 1;
    const float* p = wgt + ((size_t)co * CIN + c) * 9;
    f4u q0 = *(const f4u*)(p + 0);
    f4u q1 = *(const f4u*)(p + 4);
    f4u q2 = *(const f4u*)(p + 8);
    f4u q3 = *(const f4u*)(p + 12);
    float e16 = p[16], e17 = p[17];
    float a0[9], a1[9];
    a0[0]=q0.x; a0[1]=q0.y; a0[2]=q0.z; a0[3]=q0.w;
    a0[4]=q1.x; a0[5]=q1.y; a0[6]=q1.z; a0[7]=q1.w; a0[8]=q2.x;
    a1[0]=q2.y; a1[1]=q2.z; a1[2]=q2.w;
    a1[3]=q3.x; a1[4]=q3.y; a1[5]=q3.z; a1[6]=q3.w; a1[7]=e16; a1[8]=e17;
    int cc = c >> 5;
    int j = (c >> 1) & 3;
    int lane = (co & 15) | (((c >> 3) & 3) << 4);
    int tile_ = ((co >> 6) << 2) | ((co >> 4) & 3);
#pragma unroll
    for (int kk = 0; kk < 9; ++kk) {
      int frag = (kk * 8 + cc) * 16 + tile_;
      W2f32[(size_t)frag * 256 + lane * 4 + j] = pkh(a0[kk], a1[kk]);
    }
  }
}

// ---- main: 256 blocks x 1024 threads; block = 256 Cout x 128 px (2 rows) ----
// PRODUCER/CONSUMER wave split (r5). Waves 0..7 = consumers: strip of 32 Cout,
// full K per tap (no parity), touch only L2 af loads + LDS bf + MFMA -- never
// a gather vmcnt wait. Waves 8..15 = producers: all gathers + bilinear combine
// for the NEXT tap, depth-1 prefetch with NAMED variables (r4 lesson: register
// arrays carried across iterations spill to scratch -- FETCH exploded 21x).
// Consumer owns full K => epilogue parity-reduce through LDS deleted.
__global__ __launch_bounds__(1024, 4) void dcn_main(
    const float* __restrict__ offset, const float* __restrict__ mask,
    const float* __restrict__ bias, const u16* __restrict__ xT,
    const u16* __restrict__ W2f, float* __restrict__ out) {
  __shared__ __align__(16) u16 Bs[2][NPX * BSTR];  // 2 x 67.6 KB
  __shared__ __align__(8)  uint2 swl[1152];        // (kk,p): 4 corner wts, fp16 pairs
  __shared__ __align__(8)  ushort4 sol[1152];      // (kk,p): 4 corner position indices

  int bid = blockIdx.x;      // 256 blocks = 1/CU
  int n = bid & 7;           // XCD swizzle: XCD k serves n==k -> 2MB xT slice in L2
  int hp = bid >> 3;         // ho-pair 0..31
  int t = threadIdx.x;
  int lane = t & 63;
  int w = t >> 6;            // wave 0..15
  bool prod = (w >= 8);

  // 1) sample precompute: 9 taps x 128 px
  for (int i = t; i < 1152; i += 1024) {
    int kk = i >> 7, p = i & 127;
    int ky = kk / 3, kx = kk - ky * 3;
    int sp = (hp << 7) + p;             // = ho*64 + (p&63)
    int ho = (hp << 1) + (p >> 6);
    float dy = offset[(((size_t)n * 18 + kk * 2 + 0) << 12) + sp];
    float dx = offset[(((size_t)n * 18 + kk * 2 + 1) << 12) + sp];
    float m  = mask  [(((size_t)n * 9  + kk) << 12) + sp];
    float ys = (float)(ky + ho - 1) + dy;
    float xs = (float)(kx + (p & 63) - 1) + dx;
    float y0f = floorf(ys), x0f = floorf(xs);
    float fy = ys - y0f, fx = xs - x0f;
    int y0 = (int)y0f, x0 = (int)x0f;
    int y1 = y0 + 1, x1 = x0 + 1;
    float vy0 = (y0 >= 0 && y0 < HH) ? 1.f : 0.f;
    float vy1 = (y1 >= 0 && y1 < HH) ? 1.f : 0.f;
    float vx0 = (x0 >= 0 && x0 < WW) ? 1.f : 0.f;
    float vx1 = (x1 >= 0 && x1 < WW) ? 1.f : 0.f;
    float w0 = (1.f - fy) * (1.f - fx) * m * vy0 * vx0;
    float w1 = (1.f - fy) * fx * m * vy0 * vx1;
    float w2 = fy * (1.f - fx) * m * vy1 * vx0;
    float w3 = fy * fx * m * vy1 * vx1;
    int iy0 = min(max(y0, 0), HH - 1), iy1 = min(max(y1, 0), HH - 1);
    int ix0 = min(max(x0, 0), WW - 1), ix1 = min(max(x1, 0), WW - 1);
    ushort4 pv;
    pv.x = (u16)((iy0 << 6) + ix0);
    pv.y = (u16)((iy0 << 6) + ix1);
    pv.z = (u16)((iy1 << 6) + ix0);
    pv.w = (u16)((iy1 << 6) + ix1);
    swl[i] = make_uint2(pkh(w0, w1), pkh(w2, w3));
    sol[i] = pv;
  }
  __syncthreads();

  f32x4 acc[2][8];
#pragma unroll
  for (int a = 0; a < 2; ++a)
#pragma unroll
    for (int b2 = 0; b2 < 8; ++b2) acc[a][b2] = {0.f, 0.f, 0.f, 0.f};

  const char* xTn = (const char*)xT + ((size_t)n * HW << 9);
  int ml = lane & 15, q = lane >> 4;
  int hw32 = t >> 5;     // half-wave id 0..31 (prologue build)
  int l32 = t & 31;
  int strip = w & 7;                                  // consumer Cout strip
  int tile0 = ((strip >> 1) << 2) + ((strip & 1) << 1);
  const char* bch = xTn + (l32 << 4);
  // producer indexing: 512 threads cover 128 px x 32 chunks, 8 tasks each
  int tp = t - 512;              // 0..511 (producers only)
  int ch = tp & 31;              // 16B channel chunk
  int ph = tp >> 5;              // 0..15; px = s*16 + ph
  const char* bchp = xTn + (ch << 4);

// accumulate one register-resident corner (8 v_fma_mix_f32)
#define CMB(G, WT) do {                                                \
    float wt = (WT);                                                   \
    HU h0, h1, h2, h3;                                                 \
    h0.u = (G).x; h1.u = (G).y; h2.u = (G).z; h3.u = (G).w;            \
    s0 = __builtin_fmaf((float)h0.h.x, wt, s0);                        \
    s1 = __builtin_fmaf((float)h0.h.y, wt, s1);                        \
    s2 = __builtin_fmaf((float)h1.h.x, wt, s2);                        \
    s3 = __builtin_fmaf((float)h1.h.y, wt, s3);                        \
    s4 = __builtin_fmaf((float)h2.h.x, wt, s4);                        \
    s5 = __builtin_fmaf((float)h2.h.y, wt, s5);                        \
    s6 = __builtin_fmaf((float)h3.h.x, wt, s6);                        \
    s7 = __builtin_fmaf((float)h3.h.y, wt, s7);                        \
  } while (0)

  // monolithic build for the prologue (tap 0 into buf 0, all 16 waves)
  auto build0 = [&](int g) {
    int px = (g << 5) + hw32;
    uint2 wu = swl[px];
    ushort4 pv = sol[px];
    HU ha, hb; ha.u = wu.x; hb.u = wu.y;
    uint4 G0 = *(const uint4*)(bch + ((int)pv.x << 9));
    uint4 G1 = *(const uint4*)(bch + ((int)pv.y << 9));
    uint4 G2 = *(const uint4*)(bch + ((int)pv.z << 9));
    uint4 G3 = *(const uint4*)(bch + ((int)pv.w << 9));
    float s0=0.f,s1=0.f,s2=0.f,s3=0.f,s4=0.f,s5=0.f,s6=0.f,s7=0.f;
    CMB(G0, (float)ha.h.x);
    CMB(G1, (float)ha.h.y);
    CMB(G2, (float)hb.h.x);
    CMB(G3, (float)hb.h.y);
    uint4 pkd;
    pkd.x = pkh(s0, s1); pkd.y = pkh(s2, s3);
    pkd.z = pkh(s4, s5); pkd.w = pkh(s6, s7);
    *(uint4*)((char*)&Bs[0][0] + px * (BSTR * 2) + (l32 << 4)) = pkd;
  };

  auto af_load = [&](int fidx, int mt) {
    return *(const f16x8*)(W2f + (((size_t)((fidx << 4) + tile0 + mt)) << 9) +
                           (lane << 3));
  };

#pragma unroll
  for (int g = 0; g < 4; ++g) build0(g);

  // consumer: A-fragments for tap 0 / cc 0, prefetched (named, no arrays)
  f16x8 ca, cb;
  if (!prod) { ca = af_load(0, 0); cb = af_load(0, 1); }
  __syncthreads();

#pragma unroll 1
  for (int kk = 0; kk < 9; ++kk) {
    if (prod) {
      // ---- producer: build tap kk+1 into the other buffer ----
      if (kk < 8) {
        char* Bw = (char*)&Bs[(kk & 1) ^ 1][0];
        int base = (kk + 1) << 7;
        uint2 wA = swl[base + ph];
        ushort4 pvA = sol[base + ph];
        uint4 A0 = *(const uint4*)(bchp + ((int)pvA.x << 9));
        uint4 A1 = *(const uint4*)(bchp + ((int)pvA.y << 9));
        uint4 A2 = *(const uint4*)(bchp + ((int)pvA.z << 9));
        uint4 A3 = *(const uint4*)(bchp + ((int)pvA.w << 9));
#pragma unroll
        for (int s = 0; s < 8; ++s) {
          uint4 B0, B1, B2, B3; uint2 wB;
          if (s < 7) {   // depth-1 prefetch: issue next px's gathers first
            ushort4 pv = sol[base + ((s + 1) << 4) + ph];
            wB = swl[base + ((s + 1) << 4) + ph];
            B0 = *(const uint4*)(bchp + ((int)pv.x << 9));
            B1 = *(const uint4*)(bchp + ((int)pv.y << 9));
            B2 = *(const uint4*)(bchp + ((int)pv.z << 9));
            B3 = *(const uint4*)(bchp + ((int)pv.w << 9));
          }
          {
            HU ha, hb; ha.u = wA.x; hb.u = wA.y;
            float s0=0.f,s1=0.f,s2=0.f,s3=0.f,s4=0.f,s5=0.f,s6=0.f,s7=0.f;
            CMB(A0, (float)ha.h.x);
            CMB(A1, (float)ha.h.y);
            CMB(A2, (float)hb.h.x);
            CMB(A3, (float)hb.h.y);
            uint4 pkd;
            pkd.x = pkh(s0, s1); pkd.y = pkh(s2, s3);
            pkd.z = pkh(s4, s5); pkd.w = pkh(s6, s7);
            *(uint4*)(Bw + ((s << 4) + ph) * (BSTR * 2) + (ch << 4)) = pkd;
          }
          wA = wB; A0 = B0; A1 = B1; A2 = B2; A3 = B3;  // SSA rotate (unrolled)
        }
      }
    } else {
      // ---- consumer: full-K MFMA over Bs[kk&1]; af prefetched one cc ahead ----
      const char* Br = (const char*)&Bs[kk & 1][0];
      int fbase = kk << 3;
#pragma unroll
      for (int cc = 0; cc < 8; ++cc) {
        f16x8 na, nb;
        if (cc < 7) {
          na = af_load(fbase + cc + 1, 0);
          nb = af_load(fbase + cc + 1, 1);
        } else if (kk < 8) {
          na = af_load(fbase + 8, 0);    // next tap, cc=0
          nb = af_load(fbase + 8, 1);
        }
        __builtin_amdgcn_s_setprio(1);
#pragma unroll
        for (int nt = 0; nt < 8; ++nt) {
          f16x8 b = *(const f16x8*)(Br + ((nt << 4) + ml) * (BSTR * 2) +
                                    (cc << 6) + (q << 4));
          acc[0][nt] = __builtin_amdgcn_mfma_f32_16x16x32_f16(ca, b, acc[0][nt], 0, 0, 0);
          acc[1][nt] = __builtin_amdgcn_mfma_f32_16x16x32_f16(cb, b, acc[1][nt], 0, 0, 0);
        }
        __builtin_amdgcn_s_setprio(0);
        ca = na; cb = nb;                // SSA rotate (unrolled)
      }
    }
    __syncthreads();   // producers done writing Bs[cur^1]; consumers done reading Bs[cur]
  }

  // epilogue: consumers hold complete sums -- direct store, no LDS reduce
  if (!prod) {
    // D layout: row = q*4+r, col = ml (m91-verified); px = nt*16+ml
    size_t ob = (size_t)n * COUT * HW + ((size_t)hp << 7);
#pragma unroll
    for (int mt = 0; mt < 2; ++mt) {
#pragma unroll
      for (int r = 0; r < 4; ++r) {
        int co = (strip << 5) + (mt << 4) + (q << 2) + r;
        float bv = bias[co];
#pragma unroll
        for (int nt = 0; nt < 8; ++nt) {
          int px = (nt << 4) + ml;
          out[ob + (size_t)co * HW + px] = acc[mt][nt][r] + bv;
        }
      }
    }
  }
}

extern "C" void kernel_launch(void* const* d_in, const int* in_sizes, int n_in,
                              void* d_out, int out_size, void* d_ws, size_t ws_size,
                              hipStream_t stream) {
  const float* x      = (const float*)d_in[0];
  const float* offset = (const float*)d_in[1];
  const float* mask   = (const float*)d_in[2];
  const float* weight = (const float*)d_in[3];
  const float* bias   = (const float*)d_in[4];
  float* out = (float*)d_out;

  u16* xT  = (u16*)d_ws;                                      // 16 MB fp16
  u16* W2f = (u16*)((char*)d_ws + (size_t)NB * HW * CIN * 2); // +1.18 MB fp16

  prep_all<<<2176, 256, 0, stream>>>(x, weight, (u32*)xT, (u32*)W2f);
  dcn_main<<<256, 1024, 0, stream>>>(offset, mask, bias, xT, W2f, out);
}

// Round 6
// 150.463 us; speedup vs baseline: 1.7568x; 1.0012x over previous
//
#include <hip/hip_runtime.h>
#include <stdint.h>

typedef unsigned int u32;
typedef unsigned short u16;
typedef float f32x4 __attribute__((ext_vector_type(4)));
typedef __fp16 h16x2 __attribute__((ext_vector_type(2)));   // cvt_pkrtz native type
typedef _Float16 f16x8 __attribute__((ext_vector_type(8)));
typedef float f4u __attribute__((ext_vector_type(4), aligned(4)));  // 4B-aligned vec load

#define NB   8
#define CIN  256
#define HH   64
#define WW   64
#define HW   4096
#define COUT 256
#define NPX  128   // pixels per block (2 output rows)
#define BSTR 264   // u16 per Bs row (256 + 8 pad; 528B = 33*16B)

__device__ __forceinline__ u32 pkh(float lo, float hi) {
  h16x2 h = __builtin_amdgcn_cvt_pkrtz(lo, hi);   // v_cvt_pkrtz_f16_f32, 1 instr
  return __builtin_bit_cast(u32, h);
}
union HU { u32 u; h16x2 h; };

// ---- prep_all: blocks 0..2047 transpose x -> xT (fp16 NHWC); rest weights ----
// W2f frag layout: frag = (kk*8+cc)*16 + tile; element: lane*8+j ;
// co = (tile>>2)*64 + (tile&3)*16 + (lane&15); c = cc*32 + (lane>>4)*8 + j.
__global__ __launch_bounds__(256) void prep_all(const float* __restrict__ x,
                                                const float* __restrict__ wgt,
                                                u32* __restrict__ xT,
                                                u32* __restrict__ W2f32) {
  int b = blockIdx.x;
  int t = threadIdx.x;
  if (b < 2048) {
    __shared__ __align__(16) u32 tile[16][132];
    int n = b >> 8, hw0 = (b & 255) << 4;
    int hwq = (t & 3) << 2;          // 0,4,8,12
    int cp0 = t >> 2;                // 0..63
    const float* xb = x + (size_t)n * CIN * HW + hw0 + hwq;
#pragma unroll
    for (int it = 0; it < 2; ++it) {
      int cp = (it << 6) + cp0;      // 0..127
      int c = cp << 1;
      f4u v0 = *(const f4u*)(xb + (size_t)c * HW);
      f4u v1 = *(const f4u*)(xb + (size_t)(c + 1) * HW);
      tile[hwq + 0][cp] = pkh(v0.x, v1.x);
      tile[hwq + 1][cp] = pkh(v0.y, v1.y);
      tile[hwq + 2][cp] = pkh(v0.z, v1.z);
      tile[hwq + 3][cp] = pkh(v0.w, v1.w);
    }
    __syncthreads();
    u32* outp = xT + ((size_t)(n * HW + hw0)) * 128;
    int cq = t & 31, hb = t >> 5;    // cq: uint4 col 0..31, hb: row 0..7
#pragma unroll
    for (int it = 0; it < 2; ++it) {
      int hwl = (it << 3) + hb;
      uint4 v = *(const uint4*)&tile[hwl][cq << 2];   // ds_read_b128, 16B-aligned
      *(uint4*)(outp + (size_t)hwl * 128 + (cq << 2)) = v;  // 512B/half-wave
    }
  } else {
    // weights: thread = (co, c-pair); reads 18 consecutive floats
    int tt = (b - 2048) * 256 + t;   // 32768 total
    int cp = tt & 127, co = tt >> 7;
    int c = cp << 1;
    const float* p = wgt + ((size_t)co * CIN + c) * 9;
    f4u q0 = *(const f4u*)(p + 0);
    f4u q1 = *(const f4u*)(p + 4);
    f4u q2 = *(const f4u*)(p + 8);
    f4u q3 = *(const f4u*)(p + 12);
    float e16 = p[16], e17 = p[17];
    float a0[9], a1[9];
    a0[0]=q0.x; a0[1]=q0.y; a0[2]=q0.z; a0[3]=q0.w;
    a0[4]=q1.x; a0[5]=q1.y; a0[6]=q1.z; a0[7]=q1.w; a0[8]=q2.x;
    a1[0]=q2.y; a1[1]=q2.z; a1[2]=q2.w;
    a1[3]=q3.x; a1[4]=q3.y; a1[5]=q3.z; a1[6]=q3.w; a1[7]=e16; a1[8]=e17;
    int cc = c >> 5;
    int j = (c >> 1) & 3;
    int lane = (co & 15) | (((c >> 3) & 3) << 4);
    int tile_ = ((co >> 6) << 2) | ((co >> 4) & 3);
#pragma unroll
    for (int kk = 0; kk < 9; ++kk) {
      int frag = (kk * 8 + cc) * 16 + tile_;
      W2f32[(size_t)frag * 256 + lane * 4 + j] = pkh(a0[kk], a1[kk]);
    }
  }
}

// ---- main: 256 blocks x 768 threads (12 waves, 1 block/CU, 3 waves/SIMD) ----
// r6: rebalanced producer/consumer. Waves 0..7 consumers (32 Cout x 128 px,
// unchanged tiling) with B-FRAGMENT REGISTER DOUBLE-BUFFER: all 8 next-cc
// ds_reads + next af issued BEFORE the current MFMA cluster (r5 left the
// consumer chain LDS->MFMA serialized; 170-reg cap at 3 waves/SIMD funds the
// +32 VGPR). Waves 8..11 producers (r5 had 8, over-provisioned ~2x): 16 tasks
// each, pair-wise depth-2 prefetch. All arrays static-indexed in fully
// unrolled loops (r4 spill lesson); spill tripwire = FETCH must stay ~16MB.
__global__ __launch_bounds__(768, 3) void dcn_main(
    const float* __restrict__ offset, const float* __restrict__ mask,
    const float* __restrict__ bias, const u16* __restrict__ xT,
    const u16* __restrict__ W2f, float* __restrict__ out) {
  __shared__ __align__(16) u16 Bs[2][NPX * BSTR];  // 2 x 67.6 KB
  __shared__ __align__(8)  uint2 swl[1152];        // (kk,p): 4 corner wts, fp16 pairs
  __shared__ __align__(8)  ushort4 sol[1152];      // (kk,p): 4 corner position indices

  int bid = blockIdx.x;      // 256 blocks = 1/CU
  int n = bid & 7;           // XCD swizzle: XCD k serves n==k -> 2MB xT slice in L2
  int hp = bid >> 3;         // ho-pair 0..31
  int t = threadIdx.x;
  int lane = t & 63;
  int w = t >> 6;            // wave 0..11
  bool prod = (w >= 8);

  // 1) sample precompute: 9 taps x 128 px
  for (int i = t; i < 1152; i += 768) {
    int kk = i >> 7, p = i & 127;
    int ky = kk / 3, kx = kk - ky * 3;
    int sp = (hp << 7) + p;             // = ho*64 + (p&63)
    int ho = (hp << 1) + (p >> 6);
    float dy = offset[(((size_t)n * 18 + kk * 2 + 0) << 12) + sp];
    float dx = offset[(((size_t)n * 18 + kk * 2 + 1) << 12) + sp];
    float m  = mask  [(((size_t)n * 9  + kk) << 12) + sp];
    float ys = (float)(ky + ho - 1) + dy;
    float xs = (float)(kx + (p & 63) - 1) + dx;
    float y0f = floorf(ys), x0f = floorf(xs);
    float fy = ys - y0f, fx = xs - x0f;
    int y0 = (int)y0f, x0 = (int)x0f;
    int y1 = y0 + 1, x1 = x0 + 1;
    float vy0 = (y0 >= 0 && y0 < HH) ? 1.f : 0.f;
    float vy1 = (y1 >= 0 && y1 < HH) ? 1.f : 0.f;
    float vx0 = (x0 >= 0 && x0 < WW) ? 1.f : 0.f;
    float vx1 = (x1 >= 0 && x1 < WW) ? 1.f : 0.f;
    float w0 = (1.f - fy) * (1.f - fx) * m * vy0 * vx0;
    float w1 = (1.f - fy) * fx * m * vy0 * vx1;
    float w2 = fy * (1.f - fx) * m * vy1 * vx0;
    float w3 = fy * fx * m * vy1 * vx1;
    int iy0 = min(max(y0, 0), HH - 1), iy1 = min(max(y1, 0), HH - 1);
    int ix0 = min(max(x0, 0), WW - 1), ix1 = min(max(x1, 0), WW - 1);
    ushort4 pv;
    pv.x = (u16)((iy0 << 6) + ix0);
    pv.y = (u16)((iy0 << 6) + ix1);
    pv.z = (u16)((iy1 << 6) + ix0);
    pv.w = (u16)((iy1 << 6) + ix1);
    swl[i] = make_uint2(pkh(w0, w1), pkh(w2, w3));
    sol[i] = pv;
  }
  __syncthreads();

  f32x4 acc[2][8];
#pragma unroll
  for (int a = 0; a < 2; ++a)
#pragma unroll
    for (int b2 = 0; b2 < 8; ++b2) acc[a][b2] = {0.f, 0.f, 0.f, 0.f};

  const char* xTn = (const char*)xT + ((size_t)n * HW << 9);
  int ml = lane & 15, q = lane >> 4;
  int strip = w & 7;                                  // consumer Cout strip
  int tile0 = ((strip >> 1) << 2) + ((strip & 1) << 1);
  // producer indexing: 256 threads cover 128 px x 32 chunks, 16 tasks each
  int tp = t - 512;              // 0..255 (producers only)
  int ch = tp & 31;              // 16B channel chunk
  int ph = tp >> 5;              // 0..7; px = s*8 + ph
  const char* bchp = xTn + ((t & 31) << 4);   // chunk base (prologue + producer)

// accumulate one register-resident corner (8 v_fma_mix_f32)
#define CMB(G, WT) do {                                                \
    float wt = (WT);                                                   \
    HU h0, h1, h2, h3;                                                 \
    h0.u = (G).x; h1.u = (G).y; h2.u = (G).z; h3.u = (G).w;            \
    s0 = __builtin_fmaf((float)h0.h.x, wt, s0);                        \
    s1 = __builtin_fmaf((float)h0.h.y, wt, s1);                        \
    s2 = __builtin_fmaf((float)h1.h.x, wt, s2);                        \
    s3 = __builtin_fmaf((float)h1.h.y, wt, s3);                        \
    s4 = __builtin_fmaf((float)h2.h.x, wt, s4);                        \
    s5 = __builtin_fmaf((float)h2.h.y, wt, s5);                        \
    s6 = __builtin_fmaf((float)h3.h.x, wt, s6);                        \
    s7 = __builtin_fmaf((float)h3.h.y, wt, s7);                        \
  } while (0)

  auto af_load = [&](int fidx, int mt) {
    return *(const f16x8*)(W2f + (((size_t)((fidx << 4) + tile0 + mt)) << 9) +
                           (lane << 3));
  };

  // prologue: build tap 0 into buf 0 -- flat task loop over all 12 waves
  for (int i = t; i < 4096; i += 768) {
    int px = i >> 5, cch = i & 31;
    const char* bc = xTn + (cch << 4);
    uint2 wu = swl[px];
    ushort4 pv = sol[px];
    HU ha, hb; ha.u = wu.x; hb.u = wu.y;
    uint4 G0 = *(const uint4*)(bc + ((int)pv.x << 9));
    uint4 G1 = *(const uint4*)(bc + ((int)pv.y << 9));
    uint4 G2 = *(const uint4*)(bc + ((int)pv.z << 9));
    uint4 G3 = *(const uint4*)(bc + ((int)pv.w << 9));
    float s0=0.f,s1=0.f,s2=0.f,s3=0.f,s4=0.f,s5=0.f,s6=0.f,s7=0.f;
    CMB(G0, (float)ha.h.x);
    CMB(G1, (float)ha.h.y);
    CMB(G2, (float)hb.h.x);
    CMB(G3, (float)hb.h.y);
    uint4 pkd;
    pkd.x = pkh(s0, s1); pkd.y = pkh(s2, s3);
    pkd.z = pkh(s4, s5); pkd.w = pkh(s6, s7);
    *(uint4*)((char*)&Bs[0][0] + px * (BSTR * 2) + (cch << 4)) = pkd;
  }

  // consumer: A-fragments for tap 0 / cc 0, prefetched
  f16x8 ca, cb;
  if (!prod) { ca = af_load(0, 0); cb = af_load(0, 1); }
  __syncthreads();

#pragma unroll 1
  for (int kk = 0; kk < 9; ++kk) {
    if (prod) {
      // ---- producer: build tap kk+1 into the other buffer (16 tasks, pairs) ----
      if (kk < 8) {
        char* Bw = (char*)&Bs[(kk & 1) ^ 1][0];
        int base = (kk + 1) << 7;
        // prefetch pair 0: px = ph, ph+8
        uint2 wA = swl[base + ph];
        ushort4 pvA = sol[base + ph];
        uint4 A0 = *(const uint4*)(bchp + ((int)pvA.x << 9));
        uint4 A1 = *(const uint4*)(bchp + ((int)pvA.y << 9));
        uint4 A2 = *(const uint4*)(bchp + ((int)pvA.z << 9));
        uint4 A3 = *(const uint4*)(bchp + ((int)pvA.w << 9));
        uint2 wB = swl[base + 8 + ph];
        ushort4 pvB = sol[base + 8 + ph];
        uint4 B0 = *(const uint4*)(bchp + ((int)pvB.x << 9));
        uint4 B1 = *(const uint4*)(bchp + ((int)pvB.y << 9));
        uint4 B2 = *(const uint4*)(bchp + ((int)pvB.z << 9));
        uint4 B3 = *(const uint4*)(bchp + ((int)pvB.w << 9));
#pragma unroll
        for (int pr2 = 0; pr2 < 8; ++pr2) {
          uint4 C0, C1, C2, C3, D0, D1, D2, D3; uint2 wC, wD;
          if (pr2 < 7) {   // depth-2: issue next pair's gathers first
            int nb = base + ((pr2 + 1) << 4);
            ushort4 pvC = sol[nb + ph];
            wC = swl[nb + ph];
            C0 = *(const uint4*)(bchp + ((int)pvC.x << 9));
            C1 = *(const uint4*)(bchp + ((int)pvC.y << 9));
            C2 = *(const uint4*)(bchp + ((int)pvC.z << 9));
            C3 = *(const uint4*)(bchp + ((int)pvC.w << 9));
            ushort4 pvD = sol[nb + 8 + ph];
            wD = swl[nb + 8 + ph];
            D0 = *(const uint4*)(bchp + ((int)pvD.x << 9));
            D1 = *(const uint4*)(bchp + ((int)pvD.y << 9));
            D2 = *(const uint4*)(bchp + ((int)pvD.z << 9));
            D3 = *(const uint4*)(bchp + ((int)pvD.w << 9));
          }
          {
            int px = (pr2 << 4) + ph;
            HU ha, hb; ha.u = wA.x; hb.u = wA.y;
            float s0=0.f,s1=0.f,s2=0.f,s3=0.f,s4=0.f,s5=0.f,s6=0.f,s7=0.f;
            CMB(A0, (float)ha.h.x);
            CMB(A1, (float)ha.h.y);
            CMB(A2, (float)hb.h.x);
            CMB(A3, (float)hb.h.y);
            uint4 pkd;
            pkd.x = pkh(s0, s1); pkd.y = pkh(s2, s3);
            pkd.z = pkh(s4, s5); pkd.w = pkh(s6, s7);
            *(uint4*)(Bw + px * (BSTR * 2) + (ch << 4)) = pkd;
          }
          {
            int px = (pr2 << 4) + 8 + ph;
            HU ha, hb; ha.u = wB.x; hb.u = wB.y;
            float s0=0.f,s1=0.f,s2=0.f,s3=0.f,s4=0.f,s5=0.f,s6=0.f,s7=0.f;
            CMB(B0, (float)ha.h.x);
            CMB(B1, (float)ha.h.y);
            CMB(B2, (float)hb.h.x);
            CMB(B3, (float)hb.h.y);
            uint4 pkd;
            pkd.x = pkh(s0, s1); pkd.y = pkh(s2, s3);
            pkd.z = pkh(s4, s5); pkd.w = pkh(s6, s7);
            *(uint4*)(Bw + px * (BSTR * 2) + (ch << 4)) = pkd;
          }
          wA = wC; A0 = C0; A1 = C1; A2 = C2; A3 = C3;   // SSA rotate (unrolled)
          wB = wD; B0 = D0; B1 = D1; B2 = D2; B3 = D3;
        }
      }
    } else {
      // ---- consumer: full-K MFMA over Bs[kk&1], B-frag register dbuf ----
      const char* Br = (const char*)&Bs[kk & 1][0];
      int fbase = kk << 3;
      f16x8 bb[8], nn[8];
#pragma unroll
      for (int nt = 0; nt < 8; ++nt)
        bb[nt] = *(const f16x8*)(Br + ((nt << 4) + ml) * (BSTR * 2) + (q << 4));
#pragma unroll
      for (int cc = 0; cc < 8; ++cc) {
        f16x8 ca2, cb2;
        if (cc < 7) {     // prefetch next cc: LDS reads + af, BEFORE the MFMAs
#pragma unroll
          for (int nt = 0; nt < 8; ++nt)
            nn[nt] = *(const f16x8*)(Br + ((nt << 4) + ml) * (BSTR * 2) +
                                     ((cc + 1) << 6) + (q << 4));
          ca2 = af_load(fbase + cc + 1, 0);
          cb2 = af_load(fbase + cc + 1, 1);
        } else if (kk < 8) {
          ca2 = af_load(fbase + 8, 0);    // next tap, cc=0
          cb2 = af_load(fbase + 8, 1);
        }
        __builtin_amdgcn_s_setprio(1);
#pragma unroll
        for (int nt = 0; nt < 8; ++nt) {
          acc[0][nt] = __builtin_amdgcn_mfma_f32_16x16x32_f16(ca, bb[nt], acc[0][nt], 0, 0, 0);
          acc[1][nt] = __builtin_amdgcn_mfma_f32_16x16x32_f16(cb, bb[nt], acc[1][nt], 0, 0, 0);
        }
        __builtin_amdgcn_s_setprio(0);
        if (cc < 7) {
#pragma unroll
          for (int nt = 0; nt < 8; ++nt) bb[nt] = nn[nt];
          ca = ca2; cb = cb2;
        } else if (kk < 8) {
          ca = ca2; cb = cb2;
        }
      }
    }
    __syncthreads();   // producers done writing Bs[cur^1]; consumers done reading Bs[cur]
  }

  // epilogue: consumers hold complete sums -- direct store, no LDS reduce
  if (!prod) {
    // D layout: row = q*4+r, col = ml (m91-verified); px = nt*16+ml
    size_t ob = (size_t)n * COUT * HW + ((size_t)hp << 7);
#pragma unroll
    for (int mt = 0; mt < 2; ++mt) {
#pragma unroll
      for (int r = 0; r < 4; ++r) {
        int co = (strip << 5) + (mt << 4) + (q << 2) + r;
        float bv = bias[co];
#pragma unroll
        for (int nt = 0; nt < 8; ++nt) {
          int px = (nt << 4) + ml;
          out[ob + (size_t)co * HW + px] = acc[mt][nt][r] + bv;
        }
      }
    }
  }
}

extern "C" void kernel_launch(void* const* d_in, const int* in_sizes, int n_in,
                              void* d_out, int out_size, void* d_ws, size_t ws_size,
                              hipStream_t stream) {
  const float* x      = (const float*)d_in[0];
  const float* offset = (const float*)d_in[1];
  const float* mask   = (const float*)d_in[2];
  const float* weight = (const float*)d_in[3];
  const float* bias   = (const float*)d_in[4];
  float* out = (float*)d_out;

  u16* xT  = (u16*)d_ws;                                      // 16 MB fp16
  u16* W2f = (u16*)((char*)d_ws + (size_t)NB * HW * CIN * 2); // +1.18 MB fp16

  prep_all<<<2176, 256, 0, stream>>>(x, weight, (u32*)xT, (u32*)W2f);
  dcn_main<<<256, 768, 0, stream>>>(offset, mask, bias, xT, W2f, out);
}